// Round 18
// baseline (104.868 us; speedup 1.0000x reference)
//
#include <hip/hip_runtime.h>
#include <hip/hip_bf16.h>
#include <hip/hip_cooperative_groups.h>

namespace cg = cooperative_groups;

constexpr int HIDDEN = 256;
constexpr int BAG    = 32;
constexpr int FEAT   = 41025;   // FEATURE_COUNT + 1 (includes zero pad row)
constexpr int NJ     = 64;      // P columns: [0:32]=us-proj, [32:64]=them-proj
constexpr int NTILES = (FEAT + 63) / 64;   // 642
constexpr int LDSS   = 264;     // ushort stride per LDS row (256 + 8 pad)
constexpr int GRIDF  = 512;     // fused grid: 2 blocks/CU co-resident

using bf16x8 = __attribute__((ext_vector_type(8))) short;
using f32x4  = __attribute__((ext_vector_type(4))) float;

__device__ inline unsigned short f2bf(float f) {   // fp32 -> bf16 RNE
    __hip_bfloat16 h = __float2bfloat16(f);        // pairs fuse to v_cvt_pk_bf16_f32
    return __builtin_bit_cast(unsigned short, h);
}
__device__ inline void cvt_store(unsigned short* dst, float4 v) {
    ushort4 b; b.x = f2bf(v.x); b.y = f2bf(v.y); b.z = f2bf(v.z); b.w = f2bf(v.w);
    *reinterpret_cast<ushort4*>(dst) = b;          // 8B aligned
}

// ================= fused cooperative kernel: project + sync + gather =========
__global__ __launch_bounds__(256, 2) void fused_all(
    const int*   __restrict__ us,
    const int*   __restrict__ them,
    const float* __restrict__ emb,
    const float* __restrict__ fc1_w,
    const float* __restrict__ b1,
    const float* __restrict__ w2, const float* __restrict__ b2,
    const float* __restrict__ w3, const float* __restrict__ b3,
    unsigned short* __restrict__ P,        // bf16 [FEAT][NJ] (ws)
    float*       __restrict__ out,
    int nbg)                                // batch/8
{
    __shared__ unsigned short a_lds[64 * LDSS];   // 33 KB
    __shared__ unsigned short b_lds[64 * LDSS];   // 33 KB
    __shared__ float w2_lds[32][33];              // 4.2 KB
    __shared__ float y1_lds[8][33];               // 1.1 KB  (total ~72 KB, 2/CU)

    const int tid  = threadIdx.x;
    const int lane = tid & 63, wave = tid >> 6;
    const float4* emb4 = reinterpret_cast<const float4*>(emb);
    const float4* w4   = reinterpret_cast<const float4*>(fc1_w);

    // ---- phase 0: stage B (fc1_w as W2d[col j][k]) + w2, once per block ----
    {
        float4 bR[16];
#pragma unroll
        for (int s = 0; s < 16; ++s)
            bR[s] = w4[s * 256 + tid];
        for (int k = tid; k < 32 * 32; k += 256)
            w2_lds[k >> 5][k & 31] = w2[k];
#pragma unroll
        for (int s = 0; s < 16; ++s) {
            const int idx4 = s * 256 + tid;
            const int jr  = idx4 >> 7;             // fc1_w row (128 float4/row)
            const int kc4 = idx4 & 127;
            const int j   = jr + ((kc4 >= 64) ? 32 : 0);   // W2d column
            const int k4  = kc4 & 63;
            cvt_store(&b_lds[j * LDSS + k4 * 4], bR[s]);
        }
    }

    // ---- phase 1: grid-stride over A-tiles (R14-exact staging + MFMA) ----
    const int g = lane >> 4, ml = lane & 15;
    const int mw = wave * 16;
    for (int t = blockIdx.x; t < NTILES; t += GRIDF) {
        const int f0 = t * 64;
        float4 aR[16];
#pragma unroll
        for (int s = 0; s < 16; ++s) {
            const int idx4 = s * 256 + tid;
            const int row  = idx4 >> 6;
            const int kq4  = idx4 & 63;
            int grow = f0 + row; if (grow >= FEAT) grow = FEAT - 1;  // clamp
            aR[s] = emb4[(size_t)grow * 64 + kq4];
        }
#pragma unroll
        for (int s = 0; s < 16; ++s) {
            const int idx4 = s * 256 + tid;
            cvt_store(&a_lds[(idx4 >> 6) * LDSS + (idx4 & 63) * 4], aR[s]);
        }
        __syncthreads();                       // a_lds (and b_lds on 1st iter)

        f32x4 acc[4] = {{0.f,0.f,0.f,0.f},{0.f,0.f,0.f,0.f},
                        {0.f,0.f,0.f,0.f},{0.f,0.f,0.f,0.f}};
#pragma unroll
        for (int kt = 0; kt < 8; ++kt) {
            const bf16x8 af = *reinterpret_cast<const bf16x8*>(
                &a_lds[(mw + ml) * LDSS + kt * 32 + g * 8]);
#pragma unroll
            for (int nt = 0; nt < 4; ++nt) {
                const bf16x8 bf = *reinterpret_cast<const bf16x8*>(
                    &b_lds[(nt * 16 + ml) * LDSS + kt * 32 + g * 8]);
                acc[nt] = __builtin_amdgcn_mfma_f32_16x16x32_bf16(af, bf, acc[nt], 0, 0, 0);
            }
        }
        // D layout: row = g*4 + r, col = ml; bf16 store
#pragma unroll
        for (int nt = 0; nt < 4; ++nt) {
#pragma unroll
            for (int r = 0; r < 4; ++r) {
                const int f = f0 + mw + g * 4 + r;
                if (f < FEAT)
                    P[(size_t)f * NJ + nt * 16 + ml] = f2bf(acc[nt][r]);
            }
        }
        __syncthreads();                       // a_lds free for next tile
    }

    cg::this_grid().sync();                    // all of P written

    // ---- phase 2: gather + MLP (R16 mapping), barrier-free, grid-stride ----
    const int  l4     = lane & 15;
    const bool isB    = lane >= 32;
    const bool isThem = (lane >> 4) & 1;
    const unsigned colbyte = (isThem ? 64u : 0u) + (unsigned)l4 * 4u;
    const char* Pb = (const char*)P;
    const int  yrow = wave * 2 + (isB ? 1 : 0);
    const int  j    = lane & 31;

    for (int bg = blockIdx.x; bg < nbg; bg += GRIDF) {
        const int rowA = bg * 8 + wave * 2;
        const int rowB = rowA + 1;
        int idxA, idxB;
        {
            const int* upA = us   + (size_t)rowA * BAG;
            const int* tpA = them + (size_t)rowA * BAG;
            idxA = (lane < BAG) ? upA[lane] : tpA[lane - BAG];
            const int* upB = us   + (size_t)rowB * BAG;
            const int* tpB = them + (size_t)rowB * BAG;
            idxB = (lane < BAG) ? upB[lane] : tpB[lane - BAG];
        }

        float accx = 0.f, accy = 0.f;
#pragma unroll
        for (int i = 0; i < BAG; ++i) {
            const int fuA = __builtin_amdgcn_readlane(idxA, i);
            const int ftA = __builtin_amdgcn_readlane(idxA, BAG + i);
            const int fuB = __builtin_amdgcn_readlane(idxB, i);
            const int ftB = __builtin_amdgcn_readlane(idxB, BAG + i);
            const int fA  = isThem ? ftA : fuA;
            const int fB  = isThem ? ftB : fuB;
            const int f   = isB ? fB : fA;
            const unsigned u = *(const unsigned*)(Pb + (((unsigned)f << 7) + colbyte));
            accx += __builtin_bit_cast(float, u << 16);
            accy += __builtin_bit_cast(float, u & 0xffff0000u);
        }
        accx += __shfl_xor(accx, 16);          // us + them combine (lane ^ 16)
        accy += __shfl_xor(accy, 16);

        if (!isThem) {                         // y1 rows are wave-private: no barrier
            const int c0 = l4 * 2;
            y1_lds[yrow][c0]     = fminf(fmaxf(accx + b1[c0],     0.f), 1.f);
            y1_lds[yrow][c0 + 1] = fminf(fmaxf(accy + b1[c0 + 1], 0.f), 1.f);
        }

        float s = b2[j];
#pragma unroll
        for (int k = 0; k < 32; ++k)
            s += y1_lds[yrow][k] * w2_lds[j][k];
        float r3 = fminf(fmaxf(s, 0.f), 1.f) * w3[j];
        r3 += __shfl_xor(r3, 16); r3 += __shfl_xor(r3, 8); r3 += __shfl_xor(r3, 4);
        r3 += __shfl_xor(r3, 2);  r3 += __shfl_xor(r3, 1);
        if (j == 0) out[isB ? rowB : rowA] = tanhf(r3 + b3[0]);
    }
}

// ================= non-cooperative fallback path (R16 champion) ==============
__global__ __launch_bounds__(256, 2) void k0_project_mfma(
    const float*    __restrict__ emb,
    const float*    __restrict__ fc1_w,
    unsigned short* __restrict__ P)
{
    __shared__ unsigned short a_lds[64 * LDSS];
    __shared__ unsigned short b_lds[64 * LDSS];

    const int tid = threadIdx.x;
    const int f0  = blockIdx.x * 64;
    const float4* emb4 = reinterpret_cast<const float4*>(emb);
    const float4* w4   = reinterpret_cast<const float4*>(fc1_w);

    float4 aR[16], bR[16];
#pragma unroll
    for (int s = 0; s < 16; ++s) {
        const int idx4 = s * 256 + tid;
        const int row  = idx4 >> 6;
        const int kq4  = idx4 & 63;
        int grow = f0 + row; if (grow >= FEAT) grow = FEAT - 1;
        aR[s] = emb4[(size_t)grow * 64 + kq4];
    }
#pragma unroll
    for (int s = 0; s < 16; ++s)
        bR[s] = w4[s * 256 + tid];
#pragma unroll
    for (int s = 0; s < 16; ++s) {
        const int idx4 = s * 256 + tid;
        cvt_store(&a_lds[(idx4 >> 6) * LDSS + (idx4 & 63) * 4], aR[s]);
    }
#pragma unroll
    for (int s = 0; s < 16; ++s) {
        const int idx4 = s * 256 + tid;
        const int jr  = idx4 >> 7;
        const int kc4 = idx4 & 127;
        const int j   = jr + ((kc4 >= 64) ? 32 : 0);
        const int k4  = kc4 & 63;
        cvt_store(&b_lds[j * LDSS + k4 * 4], bR[s]);
    }
    __syncthreads();

    const int lane = tid & 63, wave = tid >> 6;
    const int g = lane >> 4, ml = lane & 15;
    const int mw = wave * 16;

    f32x4 acc[4] = {{0.f,0.f,0.f,0.f},{0.f,0.f,0.f,0.f},
                    {0.f,0.f,0.f,0.f},{0.f,0.f,0.f,0.f}};
#pragma unroll
    for (int kt = 0; kt < 8; ++kt) {
        const bf16x8 af = *reinterpret_cast<const bf16x8*>(
            &a_lds[(mw + ml) * LDSS + kt * 32 + g * 8]);
#pragma unroll
        for (int nt = 0; nt < 4; ++nt) {
            const bf16x8 bf = *reinterpret_cast<const bf16x8*>(
                &b_lds[(nt * 16 + ml) * LDSS + kt * 32 + g * 8]);
            acc[nt] = __builtin_amdgcn_mfma_f32_16x16x32_bf16(af, bf, acc[nt], 0, 0, 0);
        }
    }
#pragma unroll
    for (int nt = 0; nt < 4; ++nt) {
#pragma unroll
        for (int r = 0; r < 4; ++r) {
            const int f = f0 + mw + g * 4 + r;
            if (f < FEAT)
                P[(size_t)f * NJ + nt * 16 + ml] = f2bf(acc[nt][r]);
        }
    }
}

__global__ __launch_bounds__(256) void k1_gather_mlp(
    const int*            __restrict__ us,
    const int*            __restrict__ them,
    const unsigned short* __restrict__ P,
    const float* __restrict__ b1,
    const float* __restrict__ w2, const float* __restrict__ b2,
    const float* __restrict__ w3, const float* __restrict__ b3,
    float*       __restrict__ out)
{
    __shared__ float w2_lds[32][33];
    __shared__ float y1_lds[8][33];

    const int tid  = threadIdx.x;
    const int wave = tid >> 6;
    const int lane = tid & 63;

    for (int k = tid; k < 32 * 32; k += 256)
        w2_lds[k >> 5][k & 31] = w2[k];

    const int rowA = blockIdx.x * 8 + wave * 2;
    const int rowB = rowA + 1;
    int idxA, idxB;
    {
        const int* upA = us   + (size_t)rowA * BAG;
        const int* tpA = them + (size_t)rowA * BAG;
        idxA = (lane < BAG) ? upA[lane] : tpA[lane - BAG];
        const int* upB = us   + (size_t)rowB * BAG;
        const int* tpB = them + (size_t)rowB * BAG;
        idxB = (lane < BAG) ? upB[lane] : tpB[lane - BAG];
    }

    const int  l4     = lane & 15;
    const bool isB    = lane >= 32;
    const bool isThem = (lane >> 4) & 1;
    const unsigned colbyte = (isThem ? 64u : 0u) + (unsigned)l4 * 4u;
    const char* Pb = (const char*)P;

    float accx = 0.f, accy = 0.f;
#pragma unroll
    for (int i = 0; i < BAG; ++i) {
        const int fuA = __builtin_amdgcn_readlane(idxA, i);
        const int ftA = __builtin_amdgcn_readlane(idxA, BAG + i);
        const int fuB = __builtin_amdgcn_readlane(idxB, i);
        const int ftB = __builtin_amdgcn_readlane(idxB, BAG + i);
        const int fA  = isThem ? ftA : fuA;
        const int fB  = isThem ? ftB : fuB;
        const int f   = isB ? fB : fA;
        const unsigned u = *(const unsigned*)(Pb + (((unsigned)f << 7) + colbyte));
        accx += __builtin_bit_cast(float, u << 16);
        accy += __builtin_bit_cast(float, u & 0xffff0000u);
    }
    accx += __shfl_xor(accx, 16);
    accy += __shfl_xor(accy, 16);

    __syncthreads();

    const int yrow = wave * 2 + (isB ? 1 : 0);
    if (!isThem) {
        const int c0 = l4 * 2;
        y1_lds[yrow][c0]     = fminf(fmaxf(accx + b1[c0],     0.f), 1.f);
        y1_lds[yrow][c0 + 1] = fminf(fmaxf(accy + b1[c0 + 1], 0.f), 1.f);
    }
    __syncthreads();

    const int j = lane & 31;
    float s = b2[j];
#pragma unroll
    for (int k = 0; k < 32; ++k)
        s += y1_lds[yrow][k] * w2_lds[j][k];
    float r3 = fminf(fmaxf(s, 0.f), 1.f) * w3[j];
    r3 += __shfl_xor(r3, 16); r3 += __shfl_xor(r3, 8); r3 += __shfl_xor(r3, 4);
    r3 += __shfl_xor(r3, 2);  r3 += __shfl_xor(r3, 1);
    if (j == 0) out[isB ? rowB : rowA] = tanhf(r3 + b3[0]);
}

// ---------- fallback: R0 monolithic kernel (if ws too small) ----------
__global__ __launch_bounds__(256) void nnue_fused(
    const int*   __restrict__ us,
    const int*   __restrict__ them,
    const float* __restrict__ emb,
    const float* __restrict__ w1, const float* __restrict__ b1,
    const float* __restrict__ w2, const float* __restrict__ b2,
    const float* __restrict__ w3, const float* __restrict__ b3,
    float*       __restrict__ out)
{
    __shared__ float x_lds[4][2 * HIDDEN];
    __shared__ float y1_lds[4][32];
    __shared__ float y2_lds[4][32];

    const int tid  = threadIdx.x;
    const int wave = tid >> 6;
    const int lane = tid & 63;
    const int row  = blockIdx.x * 4 + wave;

    int myidx;
    {
        const int* up = us   + (size_t)row * BAG;
        const int* tp = them + (size_t)row * BAG;
        myidx = (lane < BAG) ? up[lane] : tp[lane - BAG];
    }
    const float4* emb4 = reinterpret_cast<const float4*>(emb);
    float4 accU = make_float4(0.f, 0.f, 0.f, 0.f);
    float4 accT = make_float4(0.f, 0.f, 0.f, 0.f);
#pragma unroll
    for (int i = 0; i < BAG; ++i) {
        const int iu = __shfl(myidx, i);
        const int it = __shfl(myidx, BAG + i);
        const float4 vu = emb4[(size_t)iu * (HIDDEN / 4) + lane];
        const float4 vt = emb4[(size_t)it * (HIDDEN / 4) + lane];
        accU.x += vu.x; accU.y += vu.y; accU.z += vu.z; accU.w += vu.w;
        accT.x += vt.x; accT.y += vt.y; accT.z += vt.z; accT.w += vt.w;
    }
    {
        float4* xv = reinterpret_cast<float4*>(&x_lds[wave][0]);
        xv[lane]      = accU;
        xv[64 + lane] = accT;
    }
    __syncthreads();
    {
        const int r    = tid >> 6;
        const int sub  = tid & 63;
        const int j    = sub >> 1;
        const int half = sub & 1;
        const float4* xr = reinterpret_cast<const float4*>(&x_lds[r][0]) + half * 64;
        const float4* wr = reinterpret_cast<const float4*>(w1 + (size_t)j * (2 * HIDDEN)) + half * 64;
        float s = 0.f;
#pragma unroll 8
        for (int k = 0; k < 64; ++k) {
            const float4 xk = xr[k];
            const float4 wk = wr[k];
            s += xk.x * wk.x + xk.y * wk.y + xk.z * wk.z + xk.w * wk.w;
        }
        s += __shfl_xor(s, 1);
        if (half == 0) { s += b1[j]; y1_lds[r][j] = fminf(fmaxf(s, 0.f), 1.f); }
    }
    __syncthreads();
    if (tid < 4 * 32) {
        const int r = tid >> 5;
        const int j = tid & 31;
        const float* wr = w2 + j * 32;
        float s = b2[j];
#pragma unroll
        for (int k = 0; k < 32; ++k) s += y1_lds[r][k] * wr[k];
        y2_lds[r][j] = fminf(fmaxf(s, 0.f), 1.f);
    }
    __syncthreads();
    if (tid < 4) {
        const int r = tid;
        float s = b3[0];
#pragma unroll
        for (int k = 0; k < 32; ++k) s += y2_lds[r][k] * w3[k];
        out[blockIdx.x * 4 + r] = tanhf(s);
    }
}

extern "C" void kernel_launch(void* const* d_in, const int* in_sizes, int n_in,
                              void* d_out, int out_size, void* d_ws, size_t ws_size,
                              hipStream_t stream) {
    const int*   us   = (const int*)  d_in[0];
    const int*   them = (const int*)  d_in[1];
    const float* emb  = (const float*)d_in[2];
    const float* w1   = (const float*)d_in[3];
    const float* b1   = (const float*)d_in[4];
    const float* w2   = (const float*)d_in[5];
    const float* b2   = (const float*)d_in[6];
    const float* w3   = (const float*)d_in[7];
    const float* b3   = (const float*)d_in[8];
    float* out = (float*)d_out;

    const int batch = in_sizes[0] / BAG;                                // 8192
    const size_t p_bytes = (size_t)FEAT * NJ * sizeof(unsigned short);  // 5.25 MB

    if (ws_size >= p_bytes && batch % 8 == 0) {
        unsigned short* P = (unsigned short*)d_ws;
        int nbg = batch / 8;                                            // 1024
        void* args[] = { (void*)&us, (void*)&them, (void*)&emb, (void*)&w1,
                         (void*)&b1, (void*)&w2, (void*)&b2, (void*)&w3,
                         (void*)&b3, (void*)&P, (void*)&out, (void*)&nbg };
        hipError_t e = hipLaunchCooperativeKernel((void*)fused_all,
                                                  dim3(GRIDF), dim3(256),
                                                  args, 0, stream);
        if (e != hipSuccess) {                 // fall back to 2-kernel champion
            const int grid0 = (FEAT + 63) / 64;
            k0_project_mfma<<<grid0, 256, 0, stream>>>(emb, w1, P);
            k1_gather_mlp<<<batch / 8, 256, 0, stream>>>(us, them, P,
                                                         b1, w2, b2, w3, b3, out);
        }
    } else {
        nnue_fused<<<(batch + 3) / 4, 256, 0, stream>>>(us, them, emb,
                                                        w1, b1, w2, b2, w3, b3, out);
    }
}

// Round 19
// 23.616 us; speedup vs baseline: 4.4406x; 4.4406x over previous
//
#include <hip/hip_runtime.h>
#include <hip/hip_bf16.h>

constexpr int HIDDEN = 256;
constexpr int BAG    = 32;
constexpr int FEAT   = 41025;   // FEATURE_COUNT + 1 (includes zero pad row)
constexpr int NJ     = 64;      // P columns: [0:32]=us-proj, [32:64]=them-proj
constexpr int NTILES = (FEAT + 63) / 64;   // 642
constexpr int LDSS   = 264;     // ushort stride per LDS row (256 + 8 pad)
constexpr int GRID0  = 512;     // 2 blocks/CU resident; grid-stride over tiles

using bf16x8 = __attribute__((ext_vector_type(8))) short;
using f32x4  = __attribute__((ext_vector_type(4))) float;

__device__ inline unsigned short f2bf(float f) {   // fp32 -> bf16 RNE
    __hip_bfloat16 h = __float2bfloat16(f);        // pairs fuse to v_cvt_pk_bf16_f32
    return __builtin_bit_cast(unsigned short, h);
}
__device__ inline void cvt_store(unsigned short* dst, float4 v) {
    ushort4 b; b.x = f2bf(v.x); b.y = f2bf(v.y); b.z = f2bf(v.z); b.w = f2bf(v.w);
    *reinterpret_cast<ushort4*>(dst) = b;          // 8B aligned
}

// ---------- k0: P(bf16) = emb @ W2d via bf16 MFMA, persistent blocks ----------
// W2d[k][j] = fc1_w[j&31][(j>>5)*256 + k].  Block = 64 rows x 64 cols, 4 waves.
// B staged ONCE per block (reused across grid-strided tiles); A staged per tile
// with the R8/R14 phase-split reg->LDS pattern.
__global__ __launch_bounds__(256, 2) void k0_project_mfma(
    const float*    __restrict__ emb,
    const float*    __restrict__ fc1_w,
    unsigned short* __restrict__ P)        // bf16 [FEAT][NJ]
{
    __shared__ unsigned short a_lds[64 * LDSS];   // A: [row][k] bf16
    __shared__ unsigned short b_lds[64 * LDSS];   // B: [n(col j)][k] bf16

    const int tid = threadIdx.x;
    const float4* emb4 = reinterpret_cast<const float4*>(emb);
    const float4* w4   = reinterpret_cast<const float4*>(fc1_w);

    // ---- stage B once: fc1_w (32x512 fp32 = 4096 float4) -> b_lds[j][k] bf16
    {
        float4 bR[16];
#pragma unroll
        for (int s = 0; s < 16; ++s)
            bR[s] = w4[s * 256 + tid];
#pragma unroll
        for (int s = 0; s < 16; ++s) {
            const int idx4 = s * 256 + tid;
            const int jr  = idx4 >> 7;             // fc1_w row (128 float4/row)
            const int kc4 = idx4 & 127;
            const int j   = jr + ((kc4 >= 64) ? 32 : 0);   // W2d column
            const int k4  = kc4 & 63;
            cvt_store(&b_lds[j * LDSS + k4 * 4], bR[s]);
        }
    }

    const int lane = tid & 63, wave = tid >> 6;
    const int g = lane >> 4, ml = lane & 15;
    const int mw = wave * 16;                  // wave's 16 rows

    for (int t = blockIdx.x; t < NTILES; t += GRID0) {
        const int f0 = t * 64;
        // ---- phase 1: issue all 16 A loads (64 rows x 64 float4, coalesced)
        float4 aR[16];
#pragma unroll
        for (int s = 0; s < 16; ++s) {
            const int idx4 = s * 256 + tid;        // 0..4095
            const int row  = idx4 >> 6;
            const int kq4  = idx4 & 63;
            int grow = f0 + row; if (grow >= FEAT) grow = FEAT - 1;   // clamp
            aR[s] = emb4[(size_t)grow * 64 + kq4];
        }
        // ---- phase 2: convert + LDS write (drains incrementally via vmcnt)
#pragma unroll
        for (int s = 0; s < 16; ++s) {
            const int idx4 = s * 256 + tid;
            cvt_store(&a_lds[(idx4 >> 6) * LDSS + (idx4 & 63) * 4], aR[s]);
        }
        __syncthreads();                       // a_lds ready (b_lds on 1st iter)

        f32x4 acc[4] = {{0.f,0.f,0.f,0.f},{0.f,0.f,0.f,0.f},
                        {0.f,0.f,0.f,0.f},{0.f,0.f,0.f,0.f}};
#pragma unroll
        for (int kt = 0; kt < 8; ++kt) {       // K = 8 x 32
            const bf16x8 af = *reinterpret_cast<const bf16x8*>(
                &a_lds[(mw + ml) * LDSS + kt * 32 + g * 8]);
#pragma unroll
            for (int nt = 0; nt < 4; ++nt) {
                const bf16x8 bf = *reinterpret_cast<const bf16x8*>(
                    &b_lds[(nt * 16 + ml) * LDSS + kt * 32 + g * 8]);
                acc[nt] = __builtin_amdgcn_mfma_f32_16x16x32_bf16(af, bf, acc[nt], 0, 0, 0);
            }
        }
        // D layout: row = g*4 + r, col = ml (verified C/D mapping); bf16 store
#pragma unroll
        for (int nt = 0; nt < 4; ++nt) {
#pragma unroll
            for (int r = 0; r < 4; ++r) {
                const int f = f0 + mw + g * 4 + r;
                if (f < FEAT)
                    P[(size_t)f * NJ + nt * 16 + ml] = f2bf(acc[nt][r]);
            }
        }
        __syncthreads();                       // a_lds free for next tile
    }
}

// ---------- k1: gather + MLP, 2 batch rows per wave, 4B gather loads (R16) ----
__global__ __launch_bounds__(256) void k1_gather_mlp(
    const int*            __restrict__ us,
    const int*            __restrict__ them,
    const unsigned short* __restrict__ P,     // bf16 [FEAT][NJ]
    const float* __restrict__ b1,
    const float* __restrict__ w2, const float* __restrict__ b2,
    const float* __restrict__ w3, const float* __restrict__ b3,
    float*       __restrict__ out)
{
    __shared__ float w2_lds[32][33];
    __shared__ float y1_lds[8][33];

    const int tid  = threadIdx.x;
    const int wave = tid >> 6;
    const int lane = tid & 63;

    for (int k = tid; k < 32 * 32; k += 256)
        w2_lds[k >> 5][k & 31] = w2[k];        // barrier deferred past gather

    const int rowA = blockIdx.x * 8 + wave * 2;
    const int rowB = rowA + 1;
    int idxA, idxB;
    {
        const int* upA = us   + (size_t)rowA * BAG;
        const int* tpA = them + (size_t)rowA * BAG;
        idxA = (lane < BAG) ? upA[lane] : tpA[lane - BAG];
        const int* upB = us   + (size_t)rowB * BAG;
        const int* tpB = them + (size_t)rowB * BAG;
        idxB = (lane < BAG) ? upB[lane] : tpB[lane - BAG];
    }

    const int  l4     = lane & 15;
    const bool isB    = lane >= 32;
    const bool isThem = (lane >> 4) & 1;
    const unsigned colbyte = (isThem ? 64u : 0u) + (unsigned)l4 * 4u;
    const char* Pb = (const char*)P;

    float accx = 0.f, accy = 0.f;              // cols c0, c0+1 (c0 = 2*l4 [+32])
#pragma unroll
    for (int i = 0; i < BAG; ++i) {
        const int fuA = __builtin_amdgcn_readlane(idxA, i);
        const int ftA = __builtin_amdgcn_readlane(idxA, BAG + i);
        const int fuB = __builtin_amdgcn_readlane(idxB, i);
        const int ftB = __builtin_amdgcn_readlane(idxB, BAG + i);
        const int fA  = isThem ? ftA : fuA;
        const int fB  = isThem ? ftB : fuB;
        const int f   = isB ? fB : fA;
        const unsigned u = *(const unsigned*)(Pb + (((unsigned)f << 7) + colbyte));
        accx += __builtin_bit_cast(float, u << 16);
        accy += __builtin_bit_cast(float, u & 0xffff0000u);
    }
    accx += __shfl_xor(accx, 16);              // us + them combine (lane ^ 16)
    accy += __shfl_xor(accy, 16);

    __syncthreads();                           // w2_lds ready

    const int yrow = wave * 2 + (isB ? 1 : 0);
    if (!isThem) {                             // lanes 0-15 (rowA), 32-47 (rowB)
        const int c0 = l4 * 2;
        y1_lds[yrow][c0]     = fminf(fmaxf(accx + b1[c0],     0.f), 1.f);
        y1_lds[yrow][c0 + 1] = fminf(fmaxf(accy + b1[c0 + 1], 0.f), 1.f);
    }
    __syncthreads();

    const int j = lane & 31;
    float s = b2[j];
#pragma unroll
    for (int k = 0; k < 32; ++k)
        s += y1_lds[yrow][k] * w2_lds[j][k];   // y1: broadcast; w2: conflict-free
    float r3 = fminf(fmaxf(s, 0.f), 1.f) * w3[j];
    r3 += __shfl_xor(r3, 16); r3 += __shfl_xor(r3, 8); r3 += __shfl_xor(r3, 4);
    r3 += __shfl_xor(r3, 2);  r3 += __shfl_xor(r3, 1);   // within 32-lane halves
    if (j == 0) out[isB ? rowB : rowA] = tanhf(r3 + b3[0]);
}

// ---------- fallback: R0 monolithic kernel (if ws too small) ----------
__global__ __launch_bounds__(256) void nnue_fused(
    const int*   __restrict__ us,
    const int*   __restrict__ them,
    const float* __restrict__ emb,
    const float* __restrict__ w1, const float* __restrict__ b1,
    const float* __restrict__ w2, const float* __restrict__ b2,
    const float* __restrict__ w3, const float* __restrict__ b3,
    float*       __restrict__ out)
{
    __shared__ float x_lds[4][2 * HIDDEN];
    __shared__ float y1_lds[4][32];
    __shared__ float y2_lds[4][32];

    const int tid  = threadIdx.x;
    const int wave = tid >> 6;
    const int lane = tid & 63;
    const int row  = blockIdx.x * 4 + wave;

    int myidx;
    {
        const int* up = us   + (size_t)row * BAG;
        const int* tp = them + (size_t)row * BAG;
        myidx = (lane < BAG) ? up[lane] : tp[lane - BAG];
    }
    const float4* emb4 = reinterpret_cast<const float4*>(emb);
    float4 accU = make_float4(0.f, 0.f, 0.f, 0.f);
    float4 accT = make_float4(0.f, 0.f, 0.f, 0.f);
#pragma unroll
    for (int i = 0; i < BAG; ++i) {
        const int iu = __shfl(myidx, i);
        const int it = __shfl(myidx, BAG + i);
        const float4 vu = emb4[(size_t)iu * (HIDDEN / 4) + lane];
        const float4 vt = emb4[(size_t)it * (HIDDEN / 4) + lane];
        accU.x += vu.x; accU.y += vu.y; accU.z += vu.z; accU.w += vu.w;
        accT.x += vt.x; accT.y += vt.y; accT.z += vt.z; accT.w += vt.w;
    }
    {
        float4* xv = reinterpret_cast<float4*>(&x_lds[wave][0]);
        xv[lane]      = accU;
        xv[64 + lane] = accT;
    }
    __syncthreads();
    {
        const int r    = tid >> 6;
        const int sub  = tid & 63;
        const int j    = sub >> 1;
        const int half = sub & 1;
        const float4* xr = reinterpret_cast<const float4*>(&x_lds[r][0]) + half * 64;
        const float4* wr = reinterpret_cast<const float4*>(w1 + (size_t)j * (2 * HIDDEN)) + half * 64;
        float s = 0.f;
#pragma unroll 8
        for (int k = 0; k < 64; ++k) {
            const float4 xk = xr[k];
            const float4 wk = wr[k];
            s += xk.x * wk.x + xk.y * wk.y + xk.z * wk.z + xk.w * wk.w;
        }
        s += __shfl_xor(s, 1);
        if (half == 0) { s += b1[j]; y1_lds[r][j] = fminf(fmaxf(s, 0.f), 1.f); }
    }
    __syncthreads();
    if (tid < 4 * 32) {
        const int r = tid >> 5;
        const int j = tid & 31;
        const float* wr = w2 + j * 32;
        float s = b2[j];
#pragma unroll
        for (int k = 0; k < 32; ++k) s += y1_lds[r][k] * wr[k];
        y2_lds[r][j] = fminf(fmaxf(s, 0.f), 1.f);
    }
    __syncthreads();
    if (tid < 4) {
        const int r = tid;
        float s = b3[0];
#pragma unroll
        for (int k = 0; k < 32; ++k) s += y2_lds[r][k] * w3[k];
        out[blockIdx.x * 4 + r] = tanhf(s);
    }
}

extern "C" void kernel_launch(void* const* d_in, const int* in_sizes, int n_in,
                              void* d_out, int out_size, void* d_ws, size_t ws_size,
                              hipStream_t stream) {
    const int*   us   = (const int*)  d_in[0];
    const int*   them = (const int*)  d_in[1];
    const float* emb  = (const float*)d_in[2];
    const float* w1   = (const float*)d_in[3];
    const float* b1   = (const float*)d_in[4];
    const float* w2   = (const float*)d_in[5];
    const float* b2   = (const float*)d_in[6];
    const float* w3   = (const float*)d_in[7];
    const float* b3   = (const float*)d_in[8];
    float* out = (float*)d_out;

    const int batch = in_sizes[0] / BAG;                                // 8192
    const size_t p_bytes = (size_t)FEAT * NJ * sizeof(unsigned short);  // 5.25 MB

    if (ws_size >= p_bytes && batch % 8 == 0) {
        unsigned short* P = (unsigned short*)d_ws;
        k0_project_mfma<<<GRID0, 256, 0, stream>>>(emb, w1, P);
        k1_gather_mlp<<<batch / 8, 256, 0, stream>>>(us, them, P,
                                                     b1, w2, b2, w3, b3, out);
    } else {
        nnue_fused<<<(batch + 3) / 4, 256, 0, stream>>>(us, them, emb,
                                                        w1, b1, w2, b2, w3, b3, out);
    }
}